// Round 2
// baseline (650.539 us; speedup 1.0000x reference)
//
#include <hip/hip_runtime.h>
#include <hip/hip_bf16.h>
#include <stdint.h>

typedef __attribute__((ext_vector_type(8))) short bf16x8;
typedef __attribute__((ext_vector_type(4))) float f32x4;
typedef __attribute__((ext_vector_type(8))) unsigned short ushort8;

#define NTOK   9232      // 16*577 tokens per stream
#define MROWS  18464     // 2*NTOK
#define MPAD   18560     // 145*128
#define NPADV  640       // padded KV length for Vt rows

__device__ __forceinline__ uint16_t f2b(float f) {
  uint32_t u = __builtin_bit_cast(uint32_t, f);
  u += 0x7fffu + ((u >> 16) & 1u);
  return (uint16_t)(u >> 16);
}

__device__ __forceinline__ f32x4 mfma16(bf16x8 a, bf16x8 b, f32x4 c) {
  return __builtin_amdgcn_mfma_f32_16x16x32_bf16(a, b, c, 0, 0, 0);
}

__device__ __forceinline__ void gl_lds16(const void* g, void* l) {
  __builtin_amdgcn_global_load_lds(
      (const __attribute__((address_space(1))) uint32_t*)g,
      (__attribute__((address_space(3))) uint32_t*)l, 16, 0, 0);
}

// ---------------------------------------------------------------- convert X
// x1,x2 fp32 [9232][1024] -> Xb bf16 [18560][1024]; pad rows zeroed.
__global__ void convert_x_kernel(const float* __restrict__ x1,
                                 const float* __restrict__ x2,
                                 uint16_t* __restrict__ Xb) {
  const size_t stride = (size_t)gridDim.x * blockDim.x;
  const size_t total8 = (size_t)MPAD * 1024 / 8;
  for (size_t i = (size_t)blockIdx.x * blockDim.x + threadIdx.x; i < total8; i += stride) {
    const size_t e = i * 8;
    const size_t row = e >> 10;
    ushort8 ov;
    if (row < (size_t)MROWS) {
      const float* src = (row < (size_t)NTOK) ? (x1 + e) : (x2 + (e - (size_t)NTOK * 1024));
      float4 a = *(const float4*)(src);
      float4 b = *(const float4*)(src + 4);
      ov[0] = f2b(a.x); ov[1] = f2b(a.y); ov[2] = f2b(a.z); ov[3] = f2b(a.w);
      ov[4] = f2b(b.x); ov[5] = f2b(b.y); ov[6] = f2b(b.z); ov[7] = f2b(b.w);
    } else {
      ov = (ushort8)0;
    }
    *(ushort8*)(Xb + e) = ov;
  }
}

// ------------------------------------------------- transpose-convert weights
// in fp32 [R][Cc] -> out bf16 [Cc][R]
__global__ void transw_kernel(const float* __restrict__ in, uint16_t* __restrict__ out,
                              int R, int Cc) {
  __shared__ float t[32][33];
  const int r0 = blockIdx.x * 32, c0 = blockIdx.y * 32;
  const int tr = threadIdx.x >> 5, tc = threadIdx.x & 31;
#pragma unroll
  for (int i = 0; i < 4; ++i)
    t[tr + i * 8][tc] = in[(size_t)(r0 + tr + i * 8) * Cc + c0 + tc];
  __syncthreads();
#pragma unroll
  for (int i = 0; i < 4; ++i) {
    const int orow = c0 + tr + i * 8;
    out[(size_t)orow * R + r0 + tc] = f2b(t[tc][tr + i * 8]);
  }
}

// ---------------------------------------------------------------- QKV GEMM
// A bf16 [18560][1024], Bt bf16 [3072][1024] (W^T).
// Epilogue scatters: Q [2][16][16][577][64] (x0.125), K same, Vt [2][16][16][64][640].
__global__ __launch_bounds__(256) void gemm_qkv_kernel(
    const uint16_t* __restrict__ A, const uint16_t* __restrict__ Bt,
    uint16_t* __restrict__ Qb, uint16_t* __restrict__ Kb, uint16_t* __restrict__ Vtb) {
  __shared__ uint16_t As[128 * 32];
  __shared__ uint16_t Bs[128 * 32];
  const int tid = threadIdx.x;
  const int w = tid >> 6, l = tid & 63;
  const int c = l & 15, g = l >> 4;
  const int bm = blockIdx.x, bn = blockIdx.y;
  const int wm = w >> 1, wn = w & 1;
  f32x4 acc[4][4] = {};

  const int srow = w * 32 + (l >> 2);
  const int scolB = (l & 3) * 16;
  const char* aG = (const char*)(A + (size_t)bm * 128 * 1024);
  const char* bG = (const char*)(Bt + (size_t)bn * 128 * 1024);
  char* aL0 = (char*)As + srow * 64 + scolB;
  char* aL1 = (char*)As + (srow + 16) * 64 + scolB;
  char* bL0 = (char*)Bs + srow * 64 + scolB;
  char* bL1 = (char*)Bs + (srow + 16) * 64 + scolB;
  const char* aG0 = aG + (size_t)srow * 2048 + scolB;
  const char* aG1 = aG + (size_t)(srow + 16) * 2048 + scolB;
  const char* bG0 = bG + (size_t)srow * 2048 + scolB;
  const char* bG1 = bG + (size_t)(srow + 16) * 2048 + scolB;

  for (int ks = 0; ks < 1024; ks += 32) {
    gl_lds16(aG0 + ks * 2, aL0);
    gl_lds16(aG1 + ks * 2, aL1);
    gl_lds16(bG0 + ks * 2, bL0);
    gl_lds16(bG1 + ks * 2, bL1);
    __syncthreads();
    bf16x8 af[4], bfv[4];
#pragma unroll
    for (int mi = 0; mi < 4; ++mi)
      af[mi] = *(const bf16x8*)((const char*)As + (wm * 64 + mi * 16 + c) * 64 + g * 16);
#pragma unroll
    for (int ni = 0; ni < 4; ++ni)
      bfv[ni] = *(const bf16x8*)((const char*)Bs + (wn * 64 + ni * 16 + c) * 64 + g * 16);
#pragma unroll
    for (int mi = 0; mi < 4; ++mi)
#pragma unroll
      for (int ni = 0; ni < 4; ++ni)
        acc[mi][ni] = mfma16(af[mi], bfv[ni], acc[mi][ni]);
    __syncthreads();
  }

  const int sArea = bn >> 3;  // 0:Q 1:K 2:V (col block of 1024)
#pragma unroll
  for (int mi = 0; mi < 4; ++mi) {
#pragma unroll
    for (int r = 0; r < 4; ++r) {
      const int R = bm * 128 + wm * 64 + mi * 16 + g * 4 + r;
      if (R >= MROWS) continue;
      const int src = (R >= NTOK) ? 1 : 0;
      const int rr = R - src * NTOK;
      const int bb = rr / 577;
      const int nn = rr - bb * 577;
#pragma unroll
      for (int ni = 0; ni < 4; ++ni) {
        const int C = bn * 128 + wn * 64 + ni * 16 + c;
        const int c10 = C & 1023;
        const int hh = c10 >> 6, dd = c10 & 63;
        const size_t bh = ((size_t)src * 16 + bb) * 16 + hh;
        const float v = acc[mi][ni][r];
        if (sArea == 0)
          Qb[(bh * 577 + nn) * 64 + dd] = f2b(v * 0.125f);
        else if (sArea == 1)
          Kb[(bh * 577 + nn) * 64 + dd] = f2b(v);
        else
          Vtb[(bh * 64 + dd) * NPADV + nn] = f2b(v);
      }
    }
  }
}

// ---------------------------------------------------------------- attention
// Flash attn, swapped QK^T. Grid = 512 problems * 10 qblocks. 4 waves x 16 qrows.
__global__ __launch_bounds__(256) void attn_kernel(
    const uint16_t* __restrict__ Qb, const uint16_t* __restrict__ Kb,
    const uint16_t* __restrict__ Vtb, uint16_t* __restrict__ O) {
  __shared__ char lds_raw[8192];
  const int tid = threadIdx.x;
  const int w = tid >> 6, l = tid & 63;
  const int c = l & 15, g = l >> 4;
  const int bid = blockIdx.x;
  const int qb = bid % 10;
  const int p = bid / 10;
  const int h = p & 15, b = (p >> 4) & 15, o = p >> 8;
  const int kvsrc = (h < 10) ? o : (1 - o);
  const uint16_t* qp = Qb + ((((size_t)o * 16 + b) * 16) + h) * 577 * 64;
  const uint16_t* kp = Kb + ((((size_t)kvsrc * 16 + b) * 16) + h) * 577 * 64;
  const uint16_t* vp = Vtb + ((((size_t)kvsrc * 16 + b) * 16) + h) * 64 * NPADV;
  char* myLds = lds_raw + w * 2048;
  const int swz = (c & 7) << 4;

  const int q0 = qb * 64 + w * 16;
  int qrow = q0 + c; if (qrow > 576) qrow = 576;
  const bf16x8 qf0 = *(const bf16x8*)(qp + (size_t)qrow * 64 + g * 8);
  const bf16x8 qf1 = *(const bf16x8*)(qp + (size_t)qrow * 64 + 32 + g * 8);

  float m_run = -3.0e38f, l_run = 0.f;
  f32x4 acc0 = {0,0,0,0}, acc1 = {0,0,0,0}, acc2 = {0,0,0,0}, acc3 = {0,0,0,0};

  for (int kv0 = 0; kv0 < 577; kv0 += 32) {
    f32x4 s0 = {0,0,0,0}, s1 = {0,0,0,0};
    {
      int kr0 = kv0 + c;      if (kr0 > 576) kr0 = 576;
      int kr1 = kv0 + 16 + c; if (kr1 > 576) kr1 = 576;
      bf16x8 ka0 = *(const bf16x8*)(kp + (size_t)kr0 * 64 + g * 8);
      bf16x8 ka1 = *(const bf16x8*)(kp + (size_t)kr0 * 64 + 32 + g * 8);
      bf16x8 kb0 = *(const bf16x8*)(kp + (size_t)kr1 * 64 + g * 8);
      bf16x8 kb1 = *(const bf16x8*)(kp + (size_t)kr1 * 64 + 32 + g * 8);
      s0 = mfma16(ka0, qf0, s0); s0 = mfma16(ka1, qf1, s0);
      s1 = mfma16(kb0, qf0, s1); s1 = mfma16(kb1, qf1, s1);
    }
    // per-lane: qi = c (column), kj = kv0 + t*16 + g*4 + r
    float sv[8];
    float mt = -3.0e38f;
#pragma unroll
    for (int r = 0; r < 4; ++r) {
      const int kj0 = kv0 + g * 4 + r;
      sv[r]     = (kj0      < 577) ? s0[r] : -3.0e38f;
      sv[4 + r] = (kj0 + 16 < 577) ? s1[r] : -3.0e38f;
      mt = fmaxf(mt, fmaxf(sv[r], sv[4 + r]));
    }
    mt = fmaxf(mt, __shfl_xor(mt, 16));
    mt = fmaxf(mt, __shfl_xor(mt, 32));
    const float m_new = fmaxf(m_run, mt);
    const float alpha = __expf(m_run - m_new);
    m_run = m_new;
    float pv[8];
    float lt = 0.f;
#pragma unroll
    for (int i = 0; i < 8; ++i) { pv[i] = __expf(sv[i] - m_new); lt += pv[i]; }
    lt += __shfl_xor(lt, 16);
    lt += __shfl_xor(lt, 32);
    l_run = l_run * alpha + lt;
#pragma unroll
    for (int r = 0; r < 4; ++r) { acc0[r] *= alpha; acc1[r] *= alpha; acc2[r] *= alpha; acc3[r] *= alpha; }
    // write P[qi=c][kj] to per-wave LDS (swizzled), packed pairs
#pragma unroll
    for (int t = 0; t < 2; ++t)
#pragma unroll
      for (int rp = 0; rp < 2; ++rp) {
        uint32_t pk = (uint32_t)f2b(pv[t * 4 + rp * 2]) | ((uint32_t)f2b(pv[t * 4 + rp * 2 + 1]) << 16);
        *(uint32_t*)(myLds + ((c * 64 + t * 32 + g * 8 + rp * 4) ^ swz)) = pk;
      }
    const bf16x8 pf = *(const bf16x8*)(myLds + ((c * 64 + g * 16) ^ swz));
    const uint16_t* vbase = vp + kv0 + g * 8;
    acc0 = mfma16(*(const bf16x8*)(vbase + (size_t)(c) * NPADV),      pf, acc0);
    acc1 = mfma16(*(const bf16x8*)(vbase + (size_t)(16 + c) * NPADV), pf, acc1);
    acc2 = mfma16(*(const bf16x8*)(vbase + (size_t)(32 + c) * NPADV), pf, acc2);
    acc3 = mfma16(*(const bf16x8*)(vbase + (size_t)(48 + c) * NPADV), pf, acc3);
  }

  const float inv = 1.0f / l_run;
  // stage out^T -> LDS [16 qrows][64 d] bf16 (swizzled), then coalesced store
#define OWRITE(ACC, DT)                                                                  \
  {                                                                                      \
    uint32_t pk0 = (uint32_t)f2b(ACC[0] * inv) | ((uint32_t)f2b(ACC[1] * inv) << 16);    \
    uint32_t pk1 = (uint32_t)f2b(ACC[2] * inv) | ((uint32_t)f2b(ACC[3] * inv) << 16);    \
    *(uint32_t*)(myLds + ((c * 128 + (DT * 16 + g * 4) * 2) ^ swz)) = pk0;               \
    *(uint32_t*)(myLds + ((c * 128 + (DT * 16 + g * 4 + 2) * 2) ^ swz)) = pk1;           \
  }
  OWRITE(acc0, 0) OWRITE(acc1, 1) OWRITE(acc2, 2) OWRITE(acc3, 3)
#undef OWRITE
#pragma unroll
  for (int pass = 0; pass < 2; ++pass) {
    const int row = l >> 2, chunk = (l & 3) + pass * 4;
    const int rswz = (row & 7) << 4;
    uint4 val = *(const uint4*)(myLds + ((row * 128 + chunk * 16) ^ rswz));
    const int qrow2 = q0 + row;
    if (qrow2 < 577) {
      const size_t orow = (size_t)o * NTOK + (size_t)b * 577 + qrow2;
      *(uint4*)(O + orow * 1024 + h * 64 + chunk * 8) = val;
    }
  }
}

// ---------------------------------------------------------------- Proj GEMM
__global__ __launch_bounds__(256) void gemm_proj_kernel(
    const uint16_t* __restrict__ A, const uint16_t* __restrict__ Bt,
    const float* __restrict__ bias, float* __restrict__ out) {
  __shared__ uint16_t As[128 * 32];
  __shared__ uint16_t Bs[128 * 32];
  const int tid = threadIdx.x;
  const int w = tid >> 6, l = tid & 63;
  const int c = l & 15, g = l >> 4;
  const int bm = blockIdx.x, bn = blockIdx.y;
  const int wm = w >> 1, wn = w & 1;
  f32x4 acc[4][4] = {};

  const int srow = w * 32 + (l >> 2);
  const int scolB = (l & 3) * 16;
  const char* aG = (const char*)(A + (size_t)bm * 128 * 1024);
  const char* bG = (const char*)(Bt + (size_t)bn * 128 * 1024);
  char* aL0 = (char*)As + srow * 64 + scolB;
  char* aL1 = (char*)As + (srow + 16) * 64 + scolB;
  char* bL0 = (char*)Bs + srow * 64 + scolB;
  char* bL1 = (char*)Bs + (srow + 16) * 64 + scolB;
  const char* aG0 = aG + (size_t)srow * 2048 + scolB;
  const char* aG1 = aG + (size_t)(srow + 16) * 2048 + scolB;
  const char* bG0 = bG + (size_t)srow * 2048 + scolB;
  const char* bG1 = bG + (size_t)(srow + 16) * 2048 + scolB;

  for (int ks = 0; ks < 1024; ks += 32) {
    gl_lds16(aG0 + ks * 2, aL0);
    gl_lds16(aG1 + ks * 2, aL1);
    gl_lds16(bG0 + ks * 2, bL0);
    gl_lds16(bG1 + ks * 2, bL1);
    __syncthreads();
    bf16x8 af[4], bfv[4];
#pragma unroll
    for (int mi = 0; mi < 4; ++mi)
      af[mi] = *(const bf16x8*)((const char*)As + (wm * 64 + mi * 16 + c) * 64 + g * 16);
#pragma unroll
    for (int ni = 0; ni < 4; ++ni)
      bfv[ni] = *(const bf16x8*)((const char*)Bs + (wn * 64 + ni * 16 + c) * 64 + g * 16);
#pragma unroll
    for (int mi = 0; mi < 4; ++mi)
#pragma unroll
      for (int ni = 0; ni < 4; ++ni)
        acc[mi][ni] = mfma16(af[mi], bfv[ni], acc[mi][ni]);
    __syncthreads();
  }

#pragma unroll
  for (int mi = 0; mi < 4; ++mi) {
#pragma unroll
    for (int r = 0; r < 4; ++r) {
      const int R = bm * 128 + wm * 64 + mi * 16 + g * 4 + r;
      if (R >= MROWS) continue;
#pragma unroll
      for (int ni = 0; ni < 4; ++ni) {
        const int C = bn * 128 + wn * 64 + ni * 16 + c;
        out[(size_t)R * 1024 + C] = acc[mi][ni][r] + bias[C];
      }
    }
  }
}

// ---------------------------------------------------------------- launch
extern "C" void kernel_launch(void* const* d_in, const int* in_sizes, int n_in,
                              void* d_out, int out_size, void* d_ws, size_t ws_size,
                              hipStream_t stream) {
  (void)in_sizes; (void)n_in; (void)out_size; (void)ws_size;
  const float* x1    = (const float*)d_in[0];
  const float* x2    = (const float*)d_in[1];
  const float* Wqkv  = (const float*)d_in[2];
  const float* Wproj = (const float*)d_in[3];
  const float* bproj = (const float*)d_in[4];
  float* out = (float*)d_out;

  char* ws = (char*)d_ws;
  size_t off = 0;
  auto alloc = [&](size_t bytes) -> char* {
    char* p = ws + off;
    off += (bytes + 255) & ~(size_t)255;
    return p;
  };
  uint16_t* Xb     = (uint16_t*)alloc((size_t)MPAD * 1024 * 2);      // also AttOut
  uint16_t* Wqkvt  = (uint16_t*)alloc((size_t)3072 * 1024 * 2);
  uint16_t* Wprojt = (uint16_t*)alloc((size_t)1024 * 1024 * 2);
  uint16_t* Qb     = (uint16_t*)alloc((size_t)512 * 577 * 64 * 2);
  uint16_t* Kb     = (uint16_t*)alloc((size_t)512 * 577 * 64 * 2);
  const size_t vtBytes = (size_t)512 * 64 * NPADV * 2;
  uint16_t* Vtb    = (uint16_t*)alloc(vtBytes);

  // zero Vt so padded kv columns are exactly 0 (never NaN/Inf) on every call
  hipMemsetAsync(Vtb, 0, vtBytes, stream);

  convert_x_kernel<<<2048, 256, 0, stream>>>(x1, x2, Xb);
  transw_kernel<<<dim3(32, 96), 256, 0, stream>>>(Wqkv, Wqkvt, 1024, 3072);
  transw_kernel<<<dim3(32, 32), 256, 0, stream>>>(Wproj, Wprojt, 1024, 1024);
  gemm_qkv_kernel<<<dim3(145, 24), 256, 0, stream>>>(Xb, Wqkvt, Qb, Kb, Vtb);
  attn_kernel<<<5120, 256, 0, stream>>>(Qb, Kb, Vtb, Xb /* AttOut, reuses X */);
  gemm_proj_kernel<<<dim3(145, 8), 256, 0, stream>>>(Xb, Wprojt, bproj, out);
}

// Round 5
// 460.327 us; speedup vs baseline: 1.4132x; 1.4132x over previous
//
#include <hip/hip_runtime.h>
#include <hip/hip_bf16.h>
#include <stdint.h>
#include <math.h>

typedef __attribute__((ext_vector_type(8))) short bf16x8;
typedef __attribute__((ext_vector_type(4))) float f32x4;
typedef __attribute__((ext_vector_type(8))) unsigned short ushort8;
typedef __attribute__((ext_vector_type(4))) unsigned int uint4v;
typedef __attribute__((ext_vector_type(2))) unsigned int uint2v;

#define NTOK   9232      // 16*577 tokens per stream
#define MROWS  18464     // 2*NTOK
#define MPAD   18560     // 145*128
#define NPADV  640       // padded KV length for Vt rows
// Q prescale: 1/sqrt(64) * log2(e) so softmax uses raw 2^x
#define QSCALE 0.18033688011112042f

__device__ __forceinline__ uint16_t f2b(float f) {
  uint32_t u = __builtin_bit_cast(uint32_t, f);
  u += 0x7fffu + ((u >> 16) & 1u);
  return (uint16_t)(u >> 16);
}

__device__ __forceinline__ uint32_t packbf(float lo, float hi) {
  return (uint32_t)f2b(lo) | ((uint32_t)f2b(hi) << 16);
}

__device__ __forceinline__ f32x4 mfma16(bf16x8 a, bf16x8 b, f32x4 c) {
  return __builtin_amdgcn_mfma_f32_16x16x32_bf16(a, b, c, 0, 0, 0);
}

__device__ __forceinline__ void gl_lds16(const void* g, void* l) {
  __builtin_amdgcn_global_load_lds(
      (const __attribute__((address_space(1))) uint32_t*)g,
      (__attribute__((address_space(3))) uint32_t*)l, 16, 0, 0);
}

// ---------------------------------------------------------------- convert X
__global__ void convert_x_kernel(const float* __restrict__ x1,
                                 const float* __restrict__ x2,
                                 uint16_t* __restrict__ Xb) {
  const size_t stride = (size_t)gridDim.x * blockDim.x;
  const size_t total8 = (size_t)MPAD * 1024 / 8;
  for (size_t i = (size_t)blockIdx.x * blockDim.x + threadIdx.x; i < total8; i += stride) {
    const size_t e = i * 8;
    const size_t row = e >> 10;
    ushort8 ov;
    if (row < (size_t)MROWS) {
      const float* src = (row < (size_t)NTOK) ? (x1 + e) : (x2 + (e - (size_t)NTOK * 1024));
      float4 a = *(const float4*)(src);
      float4 b = *(const float4*)(src + 4);
      ov[0] = f2b(a.x); ov[1] = f2b(a.y); ov[2] = f2b(a.z); ov[3] = f2b(a.w);
      ov[4] = f2b(b.x); ov[5] = f2b(b.y); ov[6] = f2b(b.z); ov[7] = f2b(b.w);
    } else {
      ov = (ushort8)0;
    }
    *(ushort8*)(Xb + e) = ov;
  }
}

// ------------------------------------------------- transpose-convert weights
__global__ void transw_kernel(const float* __restrict__ in, uint16_t* __restrict__ out,
                              int R, int Cc) {
  __shared__ float t[32][33];
  const int r0 = blockIdx.x * 32, c0 = blockIdx.y * 32;
  const int tr = threadIdx.x >> 5, tc = threadIdx.x & 31;
#pragma unroll
  for (int i = 0; i < 4; ++i)
    t[tr + i * 8][tc] = in[(size_t)(r0 + tr + i * 8) * Cc + c0 + tc];
  __syncthreads();
#pragma unroll
  for (int i = 0; i < 4; ++i) {
    const int orow = c0 + tr + i * 8;
    out[(size_t)orow * R + r0 + tc] = f2b(t[tc][tr + i * 8]);
  }
}

// ---------------------------------------------------------------- QKV GEMM
__global__ __launch_bounds__(256) void gemm_qkv_kernel(
    const uint16_t* __restrict__ A, const uint16_t* __restrict__ Bt,
    uint16_t* __restrict__ Qb, uint16_t* __restrict__ Kb, uint16_t* __restrict__ Vtb) {
  __shared__ uint16_t As[128 * 32];
  __shared__ uint16_t Bs[128 * 32];
  const int tid = threadIdx.x;
  const int w = tid >> 6, l = tid & 63;
  const int c = l & 15, g = l >> 4;
  const int bm = blockIdx.x, bn = blockIdx.y;
  const int wm = w >> 1, wn = w & 1;
  f32x4 acc[4][4] = {};

  const int srow = w * 32 + (l >> 2);
  const int scolB = (l & 3) * 16;
  const char* aG = (const char*)(A + (size_t)bm * 128 * 1024);
  const char* bG = (const char*)(Bt + (size_t)bn * 128 * 1024);
  char* aL0 = (char*)As + srow * 64 + scolB;
  char* aL1 = (char*)As + (srow + 16) * 64 + scolB;
  char* bL0 = (char*)Bs + srow * 64 + scolB;
  char* bL1 = (char*)Bs + (srow + 16) * 64 + scolB;
  const char* aG0 = aG + (size_t)srow * 2048 + scolB;
  const char* aG1 = aG + (size_t)(srow + 16) * 2048 + scolB;
  const char* bG0 = bG + (size_t)srow * 2048 + scolB;
  const char* bG1 = bG + (size_t)(srow + 16) * 2048 + scolB;

  for (int ks = 0; ks < 1024; ks += 32) {
    gl_lds16(aG0 + ks * 2, aL0);
    gl_lds16(aG1 + ks * 2, aL1);
    gl_lds16(bG0 + ks * 2, bL0);
    gl_lds16(bG1 + ks * 2, bL1);
    __syncthreads();
    bf16x8 af[4], bfv[4];
#pragma unroll
    for (int mi = 0; mi < 4; ++mi)
      af[mi] = *(const bf16x8*)((const char*)As + (wm * 64 + mi * 16 + c) * 64 + g * 16);
#pragma unroll
    for (int ni = 0; ni < 4; ++ni)
      bfv[ni] = *(const bf16x8*)((const char*)Bs + (wn * 64 + ni * 16 + c) * 64 + g * 16);
#pragma unroll
    for (int mi = 0; mi < 4; ++mi)
#pragma unroll
      for (int ni = 0; ni < 4; ++ni)
        acc[mi][ni] = mfma16(af[mi], bfv[ni], acc[mi][ni]);
    __syncthreads();
  }

  const int sArea = bn >> 3;  // 0:Q 1:K 2:V
#pragma unroll
  for (int mi = 0; mi < 4; ++mi) {
#pragma unroll
    for (int r = 0; r < 4; ++r) {
      const int R = bm * 128 + wm * 64 + mi * 16 + g * 4 + r;
      if (R >= MROWS) continue;
      const int src = (R >= NTOK) ? 1 : 0;
      const int rr = R - src * NTOK;
      const int bb = rr / 577;
      const int nn = rr - bb * 577;
#pragma unroll
      for (int ni = 0; ni < 4; ++ni) {
        const int C = bn * 128 + wn * 64 + ni * 16 + c;
        const int c10 = C & 1023;
        const int hh = c10 >> 6, dd = c10 & 63;
        const size_t bh = ((size_t)src * 16 + bb) * 16 + hh;
        const float v = acc[mi][ni][r];
        if (sArea == 0)
          Qb[(bh * 577 + nn) * 64 + dd] = f2b(v * QSCALE);
        else if (sArea == 1)
          Kb[(bh * 577 + nn) * 64 + dd] = f2b(v);
        else
          Vtb[(bh * 64 + dd) * NPADV + nn] = f2b(v);
      }
    }
  }
}

// ---------------------------------------------------------------- attention
// Cooperative flash attn on 16x16x32 MFMA ONLY (all layouts R2-verified).
// 512 problems x 3 q-chunks; 4 waves x 64 q-rows; KVB=64 staged in LDS
// (double-buffered, XOR pre-swizzled global_load_lds source); per-wave LDS
// P round-trip with the same self-cancelling swizzle.
#define KVB 64
#define ATT_NT 10
__global__ __launch_bounds__(256, 2) void attn_kernel(
    const uint16_t* __restrict__ Qb, const uint16_t* __restrict__ Kb,
    const uint16_t* __restrict__ Vtb, uint16_t* __restrict__ O) {
  __shared__ __align__(128) char smem[65536];  // Ks[2][8K] | Vs[2][8K] | P[4][8K]
  const int tid = threadIdx.x;
  const int w = tid >> 6, l = tid & 63;
  const int c = l & 15, g = l >> 4;
  const int bid = blockIdx.x;
  const int qc = bid % 3;
  const int p = bid / 3;
  const int h = p & 15, b = (p >> 4) & 15, o = p >> 8;
  const int kvsrc = (h < 10) ? o : (1 - o);
  const uint16_t* qp = Qb + (((size_t)o * 16 + b) * 16 + h) * 577 * 64;
  const uint16_t* kp = Kb + (((size_t)kvsrc * 16 + b) * 16 + h) * 577 * 64;
  const uint16_t* vp = Vtb + (((size_t)kvsrc * 16 + b) * 16 + h) * 64 * NPADV;

  const int qbase = qc * 256 + w * 64;
  const bool active = (qbase <= 576);

  // staging: lane covers 16B chunk (l&7) of row j*8+(l>>3); source chunk
  // pre-XORed so LDS[r][chunk] = G[r][chunk ^ (r&7)]
  const int sub = l >> 3;
  const int colEl = (((l & 7) ^ sub) << 3);  // element offset in row
  char* KsA = smem;
  char* VsA = smem + 16384;
  char* Pb  = smem + 32768 + w * 8192;       // per-wave P / epilogue buffer
  const int rs = (c & 7) << 4;               // swizzle for LDS rows ≡ c (mod 8)

  // ---- Q fragments: Qf[qt][kc] : lane (c,g) holds Q[qbase+qt*16+c][kc*32+g*8..+7]
  bf16x8 Qf[4][2];
  if (active) {
#pragma unroll
    for (int qt = 0; qt < 4; ++qt) {
      const int qrow = min(qbase + qt * 16 + c, 576);
      const uint16_t* qr = qp + (size_t)qrow * 64 + g * 8;
      Qf[qt][0] = *(const bf16x8*)(qr);
      Qf[qt][1] = *(const bf16x8*)(qr + 32);
    }
  }

  f32x4 acc[4][4] = {};  // [dt][qt]
  float m_run[4] = {-3.0e38f, -3.0e38f, -3.0e38f, -3.0e38f};
  float l_run[4] = {0.f, 0.f, 0.f, 0.f};

  auto STAGE = [&](int buf, int kv0) {
#pragma unroll
    for (int i = 0; i < 2; ++i) {
      const int j = w * 2 + i;
      const int row = j * 8 + sub;
      const int gk = min(kv0 + row, 576);
      gl_lds16(kp + (size_t)gk * 64 + colEl, KsA + buf * 8192 + j * 1024 + l * 16);
      gl_lds16(vp + (size_t)row * NPADV + kv0 + colEl, VsA + buf * 8192 + j * 1024 + l * 16);
    }
  };

  STAGE(0, 0);
  __syncthreads();

  for (int t = 0; t < ATT_NT; ++t) {
    if (t < ATT_NT - 1) STAGE((t + 1) & 1, (t + 1) * KVB);
    if (active) {
      const char* Kt = KsA + (t & 1) * 8192;
      const char* Vt = VsA + (t & 1) * 8192;
      // ---- K fragments: Kf[kt][kc] : lane (c,g) = K[kv0+kt*16+c][kc*32+g*8..+7]
      bf16x8 Kf[4][2];
#pragma unroll
      for (int kt = 0; kt < 4; ++kt) {
        const char* kr = Kt + (kt * 16 + c) * 128;
        Kf[kt][0] = *(const bf16x8*)(kr + ((g * 16) ^ rs));
        Kf[kt][1] = *(const bf16x8*)(kr + ((64 + g * 16) ^ rs));
      }
      float alpha_[4];
      // ---- per q-tile: QK^T, online softmax, P write (per-wave LDS)
#pragma unroll
      for (int qt = 0; qt < 4; ++qt) {
        f32x4 s[4];
#pragma unroll
        for (int kt = 0; kt < 4; ++kt) {
          f32x4 z = {0.f, 0.f, 0.f, 0.f};
          z = mfma16(Kf[kt][0], Qf[qt][0], z);
          z = mfma16(Kf[kt][1], Qf[qt][1], z);
          s[kt] = z;   // s[kt][r] = S[kv0 + kt*16 + g*4 + r][q = qbase+qt*16+c]
        }
        if (t == ATT_NT - 1) {  // mask kv > 576 (kv0 = 576: only kv-local 0 valid)
#pragma unroll
          for (int kt = 0; kt < 4; ++kt)
#pragma unroll
            for (int r = 0; r < 4; ++r) {
              if (kt == 0 && r == 0) { if (g > 0) s[kt][r] = -3.0e38f; }
              else s[kt][r] = -3.0e38f;
            }
        }
        float mt = s[0][0];
#pragma unroll
        for (int kt = 0; kt < 4; ++kt)
#pragma unroll
          for (int r = 0; r < 4; ++r) mt = fmaxf(mt, s[kt][r]);
        mt = fmaxf(mt, __shfl_xor(mt, 16));
        mt = fmaxf(mt, __shfl_xor(mt, 32));
        const float mnew = fmaxf(m_run[qt], mt);
        const float al = exp2f(m_run[qt] - mnew);
        m_run[qt] = mnew;
        alpha_[qt] = al;
        float lt = 0.f;
#pragma unroll
        for (int kt = 0; kt < 4; ++kt)
#pragma unroll
          for (int r = 0; r < 4; ++r) {
            const float pv = exp2f(s[kt][r] - mnew);
            s[kt][r] = pv;
            lt += pv;
          }
        lt += __shfl_xor(lt, 16);
        lt += __shfl_xor(lt, 32);
        l_run[qt] = l_run[qt] * al + lt;
        const int rowOff = (qt * 16 + c) * 128;
#pragma unroll
        for (int kt = 0; kt < 4; ++kt) {
          const uint2v pw = {packbf(s[kt][0], s[kt][1]), packbf(s[kt][2], s[kt][3])};
          *(uint2v*)(Pb + rowOff + ((kt * 32 + g * 8) ^ rs)) = pw;
        }
      }
      // ---- rescale accumulators
#pragma unroll
      for (int dt = 0; dt < 4; ++dt)
#pragma unroll
        for (int qt = 0; qt < 4; ++qt)
#pragma unroll
          for (int r = 0; r < 4; ++r) acc[dt][qt][r] *= alpha_[qt];
      // ---- PV: pf[qt][pc] = P[q=qt*16+c][kv pc*32+g*8..+7]; V A-frags from LDS
      bf16x8 pf[4][2];
#pragma unroll
      for (int qt = 0; qt < 4; ++qt) {
        const char* pr = Pb + (qt * 16 + c) * 128;
        pf[qt][0] = *(const bf16x8*)(pr + ((g * 16) ^ rs));
        pf[qt][1] = *(const bf16x8*)(pr + ((64 + g * 16) ^ rs));
      }
#pragma unroll
      for (int dt = 0; dt < 4; ++dt) {
        const char* vr = Vt + (dt * 16 + c) * 128;
        const bf16x8 v0 = *(const bf16x8*)(vr + ((g * 16) ^ rs));
        const bf16x8 v1 = *(const bf16x8*)(vr + ((64 + g * 16) ^ rs));
#pragma unroll
        for (int qt = 0; qt < 4; ++qt) {
          acc[dt][qt] = mfma16(v0, pf[qt][0], acc[dt][qt]);
          acc[dt][qt] = mfma16(v1, pf[qt][1], acc[dt][qt]);
        }
      }
    }
    __syncthreads();
  }

  // ---- epilogue: transpose through per-wave P buffer, coalesced store
  if (active) {
#pragma unroll
    for (int qt = 0; qt < 4; ++qt) {
      const float inv = 1.0f / l_run[qt];
      const int rowOff = (qt * 16 + c) * 128;
#pragma unroll
      for (int dt = 0; dt < 4; ++dt) {
        const uint2v pw = {packbf(acc[dt][qt][0] * inv, acc[dt][qt][1] * inv),
                           packbf(acc[dt][qt][2] * inv, acc[dt][qt][3] * inv)};
        *(uint2v*)(Pb + rowOff + ((dt * 32 + g * 8) ^ rs)) = pw;
      }
    }
    const size_t obase = ((size_t)o * NTOK + (size_t)b * 577) * 1024 + h * 64;
#pragma unroll
    for (int pass = 0; pass < 8; ++pass) {
      const int row = pass * 8 + (l >> 3);
      const int tok = qbase + row;
      const uint4v vv = *(const uint4v*)(Pb + row * 128 + (((l & 7) * 16) ^ ((row & 7) << 4)));
      if (tok <= 576)
        *(uint4v*)(O + obase + (size_t)tok * 1024 + (l & 7) * 8) = vv;
    }
  }
}

// ---------------------------------------------------------------- Proj GEMM
__global__ __launch_bounds__(256) void gemm_proj_kernel(
    const uint16_t* __restrict__ A, const uint16_t* __restrict__ Bt,
    const float* __restrict__ bias, float* __restrict__ out) {
  __shared__ uint16_t As[128 * 32];
  __shared__ uint16_t Bs[128 * 32];
  const int tid = threadIdx.x;
  const int w = tid >> 6, l = tid & 63;
  const int c = l & 15, g = l >> 4;
  const int bm = blockIdx.x, bn = blockIdx.y;
  const int wm = w >> 1, wn = w & 1;
  f32x4 acc[4][4] = {};

  const int srow = w * 32 + (l >> 2);
  const int scolB = (l & 3) * 16;
  const char* aG = (const char*)(A + (size_t)bm * 128 * 1024);
  const char* bG = (const char*)(Bt + (size_t)bn * 128 * 1024);
  char* aL0 = (char*)As + srow * 64 + scolB;
  char* aL1 = (char*)As + (srow + 16) * 64 + scolB;
  char* bL0 = (char*)Bs + srow * 64 + scolB;
  char* bL1 = (char*)Bs + (srow + 16) * 64 + scolB;
  const char* aG0 = aG + (size_t)srow * 2048 + scolB;
  const char* aG1 = aG + (size_t)(srow + 16) * 2048 + scolB;
  const char* bG0 = bG + (size_t)srow * 2048 + scolB;
  const char* bG1 = bG + (size_t)(srow + 16) * 2048 + scolB;

  for (int ks = 0; ks < 1024; ks += 32) {
    gl_lds16(aG0 + ks * 2, aL0);
    gl_lds16(aG1 + ks * 2, aL1);
    gl_lds16(bG0 + ks * 2, bL0);
    gl_lds16(bG1 + ks * 2, bL1);
    __syncthreads();
    bf16x8 af[4], bfv[4];
#pragma unroll
    for (int mi = 0; mi < 4; ++mi)
      af[mi] = *(const bf16x8*)((const char*)As + (wm * 64 + mi * 16 + c) * 64 + g * 16);
#pragma unroll
    for (int ni = 0; ni < 4; ++ni)
      bfv[ni] = *(const bf16x8*)((const char*)Bs + (wn * 64 + ni * 16 + c) * 64 + g * 16);
#pragma unroll
    for (int mi = 0; mi < 4; ++mi)
#pragma unroll
      for (int ni = 0; ni < 4; ++ni)
        acc[mi][ni] = mfma16(af[mi], bfv[ni], acc[mi][ni]);
    __syncthreads();
  }

#pragma unroll
  for (int mi = 0; mi < 4; ++mi) {
#pragma unroll
    for (int r = 0; r < 4; ++r) {
      const int R = bm * 128 + wm * 64 + mi * 16 + g * 4 + r;
      if (R >= MROWS) continue;
#pragma unroll
      for (int ni = 0; ni < 4; ++ni) {
        const int C = bn * 128 + wn * 64 + ni * 16 + c;
        out[(size_t)R * 1024 + C] = acc[mi][ni][r] + bias[C];
      }
    }
  }
}

// ---------------------------------------------------------------- launch
extern "C" void kernel_launch(void* const* d_in, const int* in_sizes, int n_in,
                              void* d_out, int out_size, void* d_ws, size_t ws_size,
                              hipStream_t stream) {
  (void)in_sizes; (void)n_in; (void)out_size; (void)ws_size;
  const float* x1    = (const float*)d_in[0];
  const float* x2    = (const float*)d_in[1];
  const float* Wqkv  = (const float*)d_in[2];
  const float* Wproj = (const float*)d_in[3];
  const float* bproj = (const float*)d_in[4];
  float* out = (float*)d_out;

  char* ws = (char*)d_ws;
  size_t off = 0;
  auto alloc = [&](size_t bytes) -> char* {
    char* p = ws + off;
    off += (bytes + 255) & ~(size_t)255;
    return p;
  };
  uint16_t* Xb     = (uint16_t*)alloc((size_t)MPAD * 1024 * 2);      // also AttOut
  uint16_t* Wqkvt  = (uint16_t*)alloc((size_t)3072 * 1024 * 2);
  uint16_t* Wprojt = (uint16_t*)alloc((size_t)1024 * 1024 * 2);
  uint16_t* Qb     = (uint16_t*)alloc((size_t)512 * 577 * 64 * 2);
  uint16_t* Kb     = (uint16_t*)alloc((size_t)512 * 577 * 64 * 2);
  const size_t vtBytes = (size_t)512 * 64 * NPADV * 2;
  uint16_t* Vtb    = (uint16_t*)alloc(vtBytes);

  // zero Vt so padded kv columns are exactly 0 on every call
  hipMemsetAsync(Vtb, 0, vtBytes, stream);

  convert_x_kernel<<<2048, 256, 0, stream>>>(x1, x2, Xb);
  transw_kernel<<<dim3(32, 96), 256, 0, stream>>>(Wqkv, Wqkvt, 1024, 3072);
  transw_kernel<<<dim3(32, 32), 256, 0, stream>>>(Wproj, Wprojt, 1024, 1024);
  gemm_qkv_kernel<<<dim3(145, 24), 256, 0, stream>>>(Xb, Wqkvt, Qb, Kb, Vtb);
  attn_kernel<<<1536, 256, 0, stream>>>(Qb, Kb, Vtb, Xb /* AttOut */);
  gemm_proj_kernel<<<dim3(145, 8), 256, 0, stream>>>(Xb, Wprojt, bproj, out);
}

// Round 6
// 424.770 us; speedup vs baseline: 1.5315x; 1.0837x over previous
//
#include <hip/hip_runtime.h>
#include <hip/hip_bf16.h>
#include <stdint.h>
#include <math.h>

typedef __attribute__((ext_vector_type(8))) short bf16x8;
typedef __attribute__((ext_vector_type(4))) float f32x4;
typedef __attribute__((ext_vector_type(8))) unsigned short ushort8;
typedef __attribute__((ext_vector_type(4))) unsigned int uint4v;
typedef __attribute__((ext_vector_type(2))) unsigned int uint2v;

#define NTOK   9232      // 16*577 tokens per stream
#define MROWS  18464     // 2*NTOK
#define MPAD   18560     // 145*128
#define NPADV  640       // padded KV length for Vt rows
// Q prescale: 1/sqrt(64) * log2(e) so softmax uses raw 2^x
#define QSCALE 0.18033688011112042f

__device__ __forceinline__ uint16_t f2b(float f) {
  uint32_t u = __builtin_bit_cast(uint32_t, f);
  u += 0x7fffu + ((u >> 16) & 1u);
  return (uint16_t)(u >> 16);
}

__device__ __forceinline__ uint32_t packbf(float lo, float hi) {
  return (uint32_t)f2b(lo) | ((uint32_t)f2b(hi) << 16);
}

__device__ __forceinline__ f32x4 mfma16(bf16x8 a, bf16x8 b, f32x4 c) {
  return __builtin_amdgcn_mfma_f32_16x16x32_bf16(a, b, c, 0, 0, 0);
}

__device__ __forceinline__ void gl_lds16(const void* g, void* l) {
  __builtin_amdgcn_global_load_lds(
      (const __attribute__((address_space(1))) uint32_t*)g,
      (__attribute__((address_space(3))) uint32_t*)l, 16, 0, 0);
}

// ---------------------------------------------------------------- convert X
__global__ void convert_x_kernel(const float* __restrict__ x1,
                                 const float* __restrict__ x2,
                                 uint16_t* __restrict__ Xb) {
  const size_t stride = (size_t)gridDim.x * blockDim.x;
  const size_t total8 = (size_t)MPAD * 1024 / 8;
  for (size_t i = (size_t)blockIdx.x * blockDim.x + threadIdx.x; i < total8; i += stride) {
    const size_t e = i * 8;
    const size_t row = e >> 10;
    ushort8 ov;
    if (row < (size_t)MROWS) {
      const float* src = (row < (size_t)NTOK) ? (x1 + e) : (x2 + (e - (size_t)NTOK * 1024));
      float4 a = *(const float4*)(src);
      float4 b = *(const float4*)(src + 4);
      ov[0] = f2b(a.x); ov[1] = f2b(a.y); ov[2] = f2b(a.z); ov[3] = f2b(a.w);
      ov[4] = f2b(b.x); ov[5] = f2b(b.y); ov[6] = f2b(b.z); ov[7] = f2b(b.w);
    } else {
      ov = (ushort8)0;
    }
    *(ushort8*)(Xb + e) = ov;
  }
}

// ------------------------------------------------- transpose-convert weights
__global__ void transw_kernel(const float* __restrict__ in, uint16_t* __restrict__ out,
                              int R, int Cc) {
  __shared__ float t[32][33];
  const int r0 = blockIdx.x * 32, c0 = blockIdx.y * 32;
  const int tr = threadIdx.x >> 5, tc = threadIdx.x & 31;
#pragma unroll
  for (int i = 0; i < 4; ++i)
    t[tr + i * 8][tc] = in[(size_t)(r0 + tr + i * 8) * Cc + c0 + tc];
  __syncthreads();
#pragma unroll
  for (int i = 0; i < 4; ++i) {
    const int orow = c0 + tr + i * 8;
    out[(size_t)orow * R + r0 + tc] = f2b(t[tc][tr + i * 8]);
  }
}

// ---------------------------------------------------------------- QKV GEMM
// 1D grid 3480 = 8 XCD-chunks x 435. Work raster: 6bm x 8bn super-tiles
// (A 1.5MB + B 2MB fits 4MB per-XCD L2).
__global__ __launch_bounds__(256) void gemm_qkv_kernel(
    const uint16_t* __restrict__ A, const uint16_t* __restrict__ Bt,
    uint16_t* __restrict__ Qb, uint16_t* __restrict__ Kb, uint16_t* __restrict__ Vtb) {
  __shared__ uint16_t As[128 * 32];
  __shared__ uint16_t Bs[128 * 32];
  const int tid = threadIdx.x;
  const int w = tid >> 6, l = tid & 63;
  const int c = l & 15, g = l >> 4;
  const int wgid = blockIdx.x;
  const int work = (wgid & 7) * 435 + (wgid >> 3);
  int bm, bn;
  {
    const int stripe = work / 144;
    if (stripe >= 24) { bm = 144; bn = work - 24 * 144; }
    else {
      const int r2 = work % 144;
      const int st8 = r2 / 48, r3 = r2 % 48;
      bm = stripe * 6 + r3 % 6;
      bn = st8 * 8 + r3 / 6;
    }
  }
  const int wm = w >> 1, wn = w & 1;
  f32x4 acc[4][4] = {};

  const int srow = w * 32 + (l >> 2);
  const int scolB = (l & 3) * 16;
  const char* aG = (const char*)(A + (size_t)bm * 128 * 1024);
  const char* bG = (const char*)(Bt + (size_t)bn * 128 * 1024);
  char* aL0 = (char*)As + srow * 64 + scolB;
  char* aL1 = (char*)As + (srow + 16) * 64 + scolB;
  char* bL0 = (char*)Bs + srow * 64 + scolB;
  char* bL1 = (char*)Bs + (srow + 16) * 64 + scolB;
  const char* aG0 = aG + (size_t)srow * 2048 + scolB;
  const char* aG1 = aG + (size_t)(srow + 16) * 2048 + scolB;
  const char* bG0 = bG + (size_t)srow * 2048 + scolB;
  const char* bG1 = bG + (size_t)(srow + 16) * 2048 + scolB;

  for (int ks = 0; ks < 1024; ks += 32) {
    gl_lds16(aG0 + ks * 2, aL0);
    gl_lds16(aG1 + ks * 2, aL1);
    gl_lds16(bG0 + ks * 2, bL0);
    gl_lds16(bG1 + ks * 2, bL1);
    __syncthreads();
    bf16x8 af[4], bfv[4];
#pragma unroll
    for (int mi = 0; mi < 4; ++mi)
      af[mi] = *(const bf16x8*)((const char*)As + (wm * 64 + mi * 16 + c) * 64 + g * 16);
#pragma unroll
    for (int ni = 0; ni < 4; ++ni)
      bfv[ni] = *(const bf16x8*)((const char*)Bs + (wn * 64 + ni * 16 + c) * 64 + g * 16);
#pragma unroll
    for (int mi = 0; mi < 4; ++mi)
#pragma unroll
      for (int ni = 0; ni < 4; ++ni)
        acc[mi][ni] = mfma16(af[mi], bfv[ni], acc[mi][ni]);
    __syncthreads();
  }

  const int sArea = bn >> 3;  // 0:Q 1:K 2:V
#pragma unroll
  for (int mi = 0; mi < 4; ++mi) {
#pragma unroll
    for (int r = 0; r < 4; ++r) {
      const int R = bm * 128 + wm * 64 + mi * 16 + g * 4 + r;
      if (R >= MROWS) continue;
      const int src = (R >= NTOK) ? 1 : 0;
      const int rr = R - src * NTOK;
      const int bb = rr / 577;
      const int nn = rr - bb * 577;
#pragma unroll
      for (int ni = 0; ni < 4; ++ni) {
        const int C = bn * 128 + wn * 64 + ni * 16 + c;
        const int c10 = C & 1023;
        const int hh = c10 >> 6, dd = c10 & 63;
        const size_t bh = ((size_t)src * 16 + bb) * 16 + hh;
        const float v = acc[mi][ni][r];
        if (sArea == 0)
          Qb[(bh * 577 + nn) * 64 + dd] = f2b(v * QSCALE);
        else if (sArea == 1)
          Kb[(bh * 577 + nn) * 64 + dd] = f2b(v);
        else
          Vtb[(bh * 64 + dd) * NPADV + nn] = f2b(v);
      }
    }
  }
}

// ---------------------------------------------------------------- attention
// Cooperative flash attn on 16x16x32 MFMA ONLY (all layouts R2-verified).
#define KVB 64
#define ATT_NT 10
__global__ __launch_bounds__(256, 2) void attn_kernel(
    const uint16_t* __restrict__ Qb, const uint16_t* __restrict__ Kb,
    const uint16_t* __restrict__ Vtb, uint16_t* __restrict__ O) {
  __shared__ __align__(128) char smem[65536];  // Ks[2][8K] | Vs[2][8K] | P[4][8K]
  const int tid = threadIdx.x;
  const int w = tid >> 6, l = tid & 63;
  const int c = l & 15, g = l >> 4;
  const int bid = blockIdx.x;
  const int qc = bid % 3;
  const int p = bid / 3;
  const int h = p & 15, b = (p >> 4) & 15, o = p >> 8;
  const int kvsrc = (h < 10) ? o : (1 - o);
  const uint16_t* qp = Qb + (((size_t)o * 16 + b) * 16 + h) * 577 * 64;
  const uint16_t* kp = Kb + (((size_t)kvsrc * 16 + b) * 16 + h) * 577 * 64;
  const uint16_t* vp = Vtb + (((size_t)kvsrc * 16 + b) * 16 + h) * 64 * NPADV;

  const int qbase = qc * 256 + w * 64;
  const bool active = (qbase <= 576);

  const int sub = l >> 3;
  const int colEl = (((l & 7) ^ sub) << 3);  // element offset in row
  char* KsA = smem;
  char* VsA = smem + 16384;
  char* Pb  = smem + 32768 + w * 8192;       // per-wave P / epilogue buffer
  const int rs = (c & 7) << 4;               // swizzle for LDS rows ≡ c (mod 8)

  bf16x8 Qf[4][2];
  if (active) {
#pragma unroll
    for (int qt = 0; qt < 4; ++qt) {
      const int qrow = min(qbase + qt * 16 + c, 576);
      const uint16_t* qr = qp + (size_t)qrow * 64 + g * 8;
      Qf[qt][0] = *(const bf16x8*)(qr);
      Qf[qt][1] = *(const bf16x8*)(qr + 32);
    }
  }

  f32x4 acc[4][4] = {};  // [dt][qt]
  float m_run[4] = {-3.0e38f, -3.0e38f, -3.0e38f, -3.0e38f};
  float l_run[4] = {0.f, 0.f, 0.f, 0.f};

  auto STAGE = [&](int buf, int kv0) {
#pragma unroll
    for (int i = 0; i < 2; ++i) {
      const int j = w * 2 + i;
      const int row = j * 8 + sub;
      const int gk = min(kv0 + row, 576);
      gl_lds16(kp + (size_t)gk * 64 + colEl, KsA + buf * 8192 + j * 1024 + l * 16);
      gl_lds16(vp + (size_t)row * NPADV + kv0 + colEl, VsA + buf * 8192 + j * 1024 + l * 16);
    }
  };

  STAGE(0, 0);
  __syncthreads();

  for (int t = 0; t < ATT_NT; ++t) {
    if (t < ATT_NT - 1) STAGE((t + 1) & 1, (t + 1) * KVB);
    if (active) {
      const char* Kt = KsA + (t & 1) * 8192;
      const char* Vt = VsA + (t & 1) * 8192;
      bf16x8 Kf[4][2];
#pragma unroll
      for (int kt = 0; kt < 4; ++kt) {
        const char* kr = Kt + (kt * 16 + c) * 128;
        Kf[kt][0] = *(const bf16x8*)(kr + ((g * 16) ^ rs));
        Kf[kt][1] = *(const bf16x8*)(kr + ((64 + g * 16) ^ rs));
      }
      float alpha_[4];
#pragma unroll
      for (int qt = 0; qt < 4; ++qt) {
        f32x4 s[4];
#pragma unroll
        for (int kt = 0; kt < 4; ++kt) {
          f32x4 z = {0.f, 0.f, 0.f, 0.f};
          z = mfma16(Kf[kt][0], Qf[qt][0], z);
          z = mfma16(Kf[kt][1], Qf[qt][1], z);
          s[kt] = z;
        }
        if (t == ATT_NT - 1) {
#pragma unroll
          for (int kt = 0; kt < 4; ++kt)
#pragma unroll
            for (int r = 0; r < 4; ++r) {
              if (kt == 0 && r == 0) { if (g > 0) s[kt][r] = -3.0e38f; }
              else s[kt][r] = -3.0e38f;
            }
        }
        float mt = s[0][0];
#pragma unroll
        for (int kt = 0; kt < 4; ++kt)
#pragma unroll
          for (int r = 0; r < 4; ++r) mt = fmaxf(mt, s[kt][r]);
        mt = fmaxf(mt, __shfl_xor(mt, 16));
        mt = fmaxf(mt, __shfl_xor(mt, 32));
        const float mnew = fmaxf(m_run[qt], mt);
        const float al = exp2f(m_run[qt] - mnew);
        m_run[qt] = mnew;
        alpha_[qt] = al;
        float lt = 0.f;
#pragma unroll
        for (int kt = 0; kt < 4; ++kt)
#pragma unroll
          for (int r = 0; r < 4; ++r) {
            const float pv = exp2f(s[kt][r] - mnew);
            s[kt][r] = pv;
            lt += pv;
          }
        lt += __shfl_xor(lt, 16);
        lt += __shfl_xor(lt, 32);
        l_run[qt] = l_run[qt] * al + lt;
        const int rowOff = (qt * 16 + c) * 128;
#pragma unroll
        for (int kt = 0; kt < 4; ++kt) {
          const uint2v pw = {packbf(s[kt][0], s[kt][1]), packbf(s[kt][2], s[kt][3])};
          *(uint2v*)(Pb + rowOff + ((kt * 32 + g * 8) ^ rs)) = pw;
        }
      }
#pragma unroll
      for (int dt = 0; dt < 4; ++dt)
#pragma unroll
        for (int qt = 0; qt < 4; ++qt)
#pragma unroll
          for (int r = 0; r < 4; ++r) acc[dt][qt][r] *= alpha_[qt];
      bf16x8 pf[4][2];
#pragma unroll
      for (int qt = 0; qt < 4; ++qt) {
        const char* pr = Pb + (qt * 16 + c) * 128;
        pf[qt][0] = *(const bf16x8*)(pr + ((g * 16) ^ rs));
        pf[qt][1] = *(const bf16x8*)(pr + ((64 + g * 16) ^ rs));
      }
#pragma unroll
      for (int dt = 0; dt < 4; ++dt) {
        const char* vr = Vt + (dt * 16 + c) * 128;
        const bf16x8 v0 = *(const bf16x8*)(vr + ((g * 16) ^ rs));
        const bf16x8 v1 = *(const bf16x8*)(vr + ((64 + g * 16) ^ rs));
#pragma unroll
        for (int qt = 0; qt < 4; ++qt) {
          acc[dt][qt] = mfma16(v0, pf[qt][0], acc[dt][qt]);
          acc[dt][qt] = mfma16(v1, pf[qt][1], acc[dt][qt]);
        }
      }
    }
    __syncthreads();
  }

  if (active) {
#pragma unroll
    for (int qt = 0; qt < 4; ++qt) {
      const float inv = 1.0f / l_run[qt];
      const int rowOff = (qt * 16 + c) * 128;
#pragma unroll
      for (int dt = 0; dt < 4; ++dt) {
        const uint2v pw = {packbf(acc[dt][qt][0] * inv, acc[dt][qt][1] * inv),
                           packbf(acc[dt][qt][2] * inv, acc[dt][qt][3] * inv)};
        *(uint2v*)(Pb + rowOff + ((dt * 32 + g * 8) ^ rs)) = pw;
      }
    }
    const size_t obase = ((size_t)o * NTOK + (size_t)b * 577) * 1024 + h * 64;
#pragma unroll
    for (int pass = 0; pass < 8; ++pass) {
      const int row = pass * 8 + (l >> 3);
      const int tok = qbase + row;
      const uint4v vv = *(const uint4v*)(Pb + row * 128 + (((l & 7) * 16) ^ ((row & 7) << 4)));
      if (tok <= 576)
        *(uint4v*)(O + obase + (size_t)tok * 1024 + (l & 7) * 8) = vv;
    }
  }
}

// ---------------------------------------------------------------- Proj GEMM
// 1D grid 1160 = 8 XCD-chunks x 145. Raster: 6bm x 8bn super-tiles.
__global__ __launch_bounds__(256) void gemm_proj_kernel(
    const uint16_t* __restrict__ A, const uint16_t* __restrict__ Bt,
    const float* __restrict__ bias, float* __restrict__ out) {
  __shared__ uint16_t As[128 * 32];
  __shared__ uint16_t Bs[128 * 32];
  const int tid = threadIdx.x;
  const int w = tid >> 6, l = tid & 63;
  const int c = l & 15, g = l >> 4;
  const int wgid = blockIdx.x;
  const int work = (wgid & 7) * 145 + (wgid >> 3);
  int bm, bn;
  {
    const int stripe = work / 48;
    if (stripe >= 24) { bm = 144; bn = work - 24 * 48; }
    else { const int r3 = work % 48; bm = stripe * 6 + r3 % 6; bn = r3 / 6; }
  }
  const int wm = w >> 1, wn = w & 1;
  f32x4 acc[4][4] = {};

  const int srow = w * 32 + (l >> 2);
  const int scolB = (l & 3) * 16;
  const char* aG = (const char*)(A + (size_t)bm * 128 * 1024);
  const char* bG = (const char*)(Bt + (size_t)bn * 128 * 1024);
  char* aL0 = (char*)As + srow * 64 + scolB;
  char* aL1 = (char*)As + (srow + 16) * 64 + scolB;
  char* bL0 = (char*)Bs + srow * 64 + scolB;
  char* bL1 = (char*)Bs + (srow + 16) * 64 + scolB;
  const char* aG0 = aG + (size_t)srow * 2048 + scolB;
  const char* aG1 = aG + (size_t)(srow + 16) * 2048 + scolB;
  const char* bG0 = bG + (size_t)srow * 2048 + scolB;
  const char* bG1 = bG + (size_t)(srow + 16) * 2048 + scolB;

  for (int ks = 0; ks < 1024; ks += 32) {
    gl_lds16(aG0 + ks * 2, aL0);
    gl_lds16(aG1 + ks * 2, aL1);
    gl_lds16(bG0 + ks * 2, bL0);
    gl_lds16(bG1 + ks * 2, bL1);
    __syncthreads();
    bf16x8 af[4], bfv[4];
#pragma unroll
    for (int mi = 0; mi < 4; ++mi)
      af[mi] = *(const bf16x8*)((const char*)As + (wm * 64 + mi * 16 + c) * 64 + g * 16);
#pragma unroll
    for (int ni = 0; ni < 4; ++ni)
      bfv[ni] = *(const bf16x8*)((const char*)Bs + (wn * 64 + ni * 16 + c) * 64 + g * 16);
#pragma unroll
    for (int mi = 0; mi < 4; ++mi)
#pragma unroll
      for (int ni = 0; ni < 4; ++ni)
        acc[mi][ni] = mfma16(af[mi], bfv[ni], acc[mi][ni]);
    __syncthreads();
  }

#pragma unroll
  for (int mi = 0; mi < 4; ++mi) {
#pragma unroll
    for (int r = 0; r < 4; ++r) {
      const int R = bm * 128 + wm * 64 + mi * 16 + g * 4 + r;
      if (R >= MROWS) continue;
#pragma unroll
      for (int ni = 0; ni < 4; ++ni) {
        const int C = bn * 128 + wn * 64 + ni * 16 + c;
        out[(size_t)R * 1024 + C] = acc[mi][ni][r] + bias[C];
      }
    }
  }
}

// ---------------------------------------------------------------- launch
extern "C" void kernel_launch(void* const* d_in, const int* in_sizes, int n_in,
                              void* d_out, int out_size, void* d_ws, size_t ws_size,
                              hipStream_t stream) {
  (void)in_sizes; (void)n_in; (void)out_size; (void)ws_size;
  const float* x1    = (const float*)d_in[0];
  const float* x2    = (const float*)d_in[1];
  const float* Wqkv  = (const float*)d_in[2];
  const float* Wproj = (const float*)d_in[3];
  const float* bproj = (const float*)d_in[4];
  float* out = (float*)d_out;

  char* ws = (char*)d_ws;
  size_t off = 0;
  auto alloc = [&](size_t bytes) -> char* {
    char* p = ws + off;
    off += (bytes + 255) & ~(size_t)255;
    return p;
  };
  uint16_t* Xb     = (uint16_t*)alloc((size_t)MPAD * 1024 * 2);      // also AttOut
  uint16_t* Wqkvt  = (uint16_t*)alloc((size_t)3072 * 1024 * 2);
  uint16_t* Wprojt = (uint16_t*)alloc((size_t)1024 * 1024 * 2);
  uint16_t* Qb     = (uint16_t*)alloc((size_t)512 * 577 * 64 * 2);
  uint16_t* Kb     = (uint16_t*)alloc((size_t)512 * 577 * 64 * 2);
  const size_t vtBytes = (size_t)512 * 64 * NPADV * 2;
  uint16_t* Vtb    = (uint16_t*)alloc(vtBytes);

  // zero Vt so padded kv columns are exactly 0 on every call
  hipMemsetAsync(Vtb, 0, vtBytes, stream);

  convert_x_kernel<<<2048, 256, 0, stream>>>(x1, x2, Xb);
  transw_kernel<<<dim3(32, 96), 256, 0, stream>>>(Wqkv, Wqkvt, 1024, 3072);
  transw_kernel<<<dim3(32, 32), 256, 0, stream>>>(Wproj, Wprojt, 1024, 1024);
  gemm_qkv_kernel<<<3480, 256, 0, stream>>>(Xb, Wqkvt, Qb, Kb, Vtb);
  attn_kernel<<<1536, 256, 0, stream>>>(Qb, Kb, Vtb, Xb /* AttOut */);
  gemm_proj_kernel<<<1160, 256, 0, stream>>>(Xb, Wprojt, bproj, out);
}